// Round 12
// baseline (205.531 us; speedup 1.0000x reference)
//
#include <hip/hip_runtime.h>
#include <hip/hip_bf16.h>
#include <cstdint>

typedef __hip_bfloat16 bf16;
typedef __attribute__((ext_vector_type(8))) short short8;
typedef __attribute__((ext_vector_type(4))) float f32x4;
typedef unsigned int u32;

#define BB 2
#define LL 2048
#define DM 1024
#define DI 2048
#define DS 128
#define NH 32
#define HD 64
#define CONVD 2304
#define DPROJ 4384
#define DPAD 4480
#define NBL (BB*LL)
#define NCHK 16
#define CLEN 128

__device__ __forceinline__ float bf2f(bf16 v) { return __bfloat162float(v); }
__device__ __forceinline__ bf16 f2bf(float f) { return __float2bfloat16(f); }
__device__ __forceinline__ unsigned short f2bfu(float f) {
  bf16 t = __float2bfloat16(f); return *(unsigned short*)&t;
}
__device__ __forceinline__ float bfu2f(unsigned short u) {
  u32 b = ((u32)u) << 16; return *(float*)&b;
}

__device__ __forceinline__ void gload16(const void* g, void* l) {
  __builtin_amdgcn_global_load_lds(
      (const __attribute__((address_space(1))) u32*)g,
      (__attribute__((address_space(3))) u32*)l, 16, 0, 0);
}

template<int N> __device__ __forceinline__ void waitvm() {
  __builtin_amdgcn_sched_barrier(0);
  if constexpr (N == 0) asm volatile("s_waitcnt vmcnt(0)" ::: "memory");
  else if constexpr (N == 3) asm volatile("s_waitcnt vmcnt(3)" ::: "memory");
  else if constexpr (N == 4) asm volatile("s_waitcnt vmcnt(4)" ::: "memory");
  __builtin_amdgcn_sched_barrier(0);
}
__device__ __forceinline__ void rawbar() {
  __builtin_amdgcn_sched_barrier(0);
  __builtin_amdgcn_s_barrier();
  __builtin_amdgcn_sched_barrier(0);
}

// ---------------- fused f32 -> bf16 casts (x, in_proj_w, out_proj_w) ----------------
__global__ __launch_bounds__(256)
void k_cast3(const float* __restrict__ s0, bf16* __restrict__ d0, int n0,
             const float* __restrict__ s1, bf16* __restrict__ d1, int n1,
             const float* __restrict__ s2, bf16* __restrict__ d2, int n2)
{
  int i = blockIdx.x * blockDim.x + threadIdx.x;
  const int stride = gridDim.x * blockDim.x;
  const int total = n0 + n1 + n2;
  for (; i < total; i += stride) {
    const float* s; bf16* d; int j = i;
    if (j < n0)            { s = s0; d = d0; }
    else if (j < n0 + n1)  { s = s1; d = d1; j -= n0; }
    else                   { s = s2; d = d2; j -= n0 + n1; }
    const float4 v = ((const float4*)s)[j];
    u32 w0 = (u32)f2bfu(v.x) | ((u32)f2bfu(v.y) << 16);
    u32 w1 = (u32)f2bfu(v.z) | ((u32)f2bfu(v.w) << 16);
    *(uint2*)(d + (size_t)j*4) = make_uint2(w0, w1);
  }
}

// ---------------- GEMM (NT), 8 waves, dbuf + lookahead (counted vmcnt) + LDS swizzle ----------------
// MODE 0: f32 out + bf16 residual. MODE 1: bf16 out (LDS-vectorized) + f32 dtraw side-write.
template<int TM, int MODE>
__global__ __launch_bounds__(512)
void k_gemm_nt(const bf16* __restrict__ A, const bf16* __restrict__ W,
               int K, int Nw, int ldo,
               float* __restrict__ outf, const bf16* __restrict__ residb,
               bf16* __restrict__ outb, float* __restrict__ dtraw)
{
  constexpr int BUFE = (TM + 128) * 64;              // ushorts per buffer
  constexpr int LPT  = TM/64 + 2;                    // gloads per wave per tile
  __shared__ __align__(16) unsigned short S[2*BUFE]; // dbuf; reused as epilogue staging
  const int tid = threadIdx.x;
  const int w = tid >> 6, lane = tid & 63;
  const int m0 = blockIdx.x * TM, n0 = blockIdx.y * 128;
  const int wr = w >> 2, wc = w & 3;                 // 2 (M) x 4 (N) wave grid
  constexpr int MI = TM / 32;
  f32x4 acc[MI][2] = {};
  const int r0 = lane & 15;
  const int kq = (lane >> 4) * 8;
  // swizzle: LDS slot (row, pcol) holds logical col pcol ^ ((row&7)*8); pre-swizzled source.
  const int srow = lane >> 3;
  const int scol = ((lane & 7) ^ (lane >> 3)) << 3;  // pre-swizzled source col (elems)
  const int swz  = (r0 & 7) << 3;                    // read-side XOR (elems)
  const int NT = K >> 6;

#define STAGE(T, BUF) {                                                          \
    const int k0s = (T) << 6;                                                    \
    unsigned short* dst = S + (BUF) * BUFE;                                      \
    _Pragma("unroll")                                                            \
    for (int it = 0; it < TM/64; ++it) {                                         \
      const int seg = it*8 + w;                                                  \
      const int row = seg*8 + srow;                                              \
      gload16(A + (size_t)(m0 + row)*K + (k0s + scol), (char*)dst + seg*1024);   \
    }                                                                            \
    unsigned short* dstW = dst + TM*64;                                          \
    _Pragma("unroll")                                                            \
    for (int it = 0; it < 2; ++it) {                                             \
      const int seg = it*8 + w;                                                  \
      const int row = seg*8 + srow;                                              \
      int rw = n0 + row; rw = (rw < Nw) ? rw : (Nw - 1);                         \
      gload16(W + (size_t)rw*K + (k0s + scol), (char*)dstW + seg*1024);          \
    }                                                                            \
  }

  // prologue: stage tiles 0 and 1
  STAGE(0, 0);
  STAGE(1, 1);
  waitvm<LPT>();          // tile 0 complete, tile 1 still in flight
  rawbar();

  for (int t = 0; t < NT; ++t) {
    const int cur = t & 1;
    const unsigned short* As = S + cur*BUFE;
    const unsigned short* Ws = As + TM*64;
    #pragma unroll
    for (int kk = 0; kk < 64; kk += 32) {
      const int ce = (kk + kq) ^ swz;
      short8 af[MI], bw[2];
      #pragma unroll
      for (int mi = 0; mi < MI; ++mi)
        af[mi] = *(const short8*)(As + (wr*(TM/2) + mi*16 + r0)*64 + ce);
      #pragma unroll
      for (int ni = 0; ni < 2; ++ni)
        bw[ni] = *(const short8*)(Ws + (wc*32 + ni*16 + r0)*64 + ce);
      #pragma unroll
      for (int mi = 0; mi < MI; ++mi)
        #pragma unroll
        for (int ni = 0; ni < 2; ++ni)
          acc[mi][ni] = __builtin_amdgcn_mfma_f32_16x16x32_bf16(af[mi], bw[ni], acc[mi][ni], 0, 0, 0);
    }
    rawbar();                      // all waves done reading buf[cur]
    if (t + 2 < NT) {
      STAGE(t + 2, cur);           // overwrite the buffer just freed
      waitvm<LPT>();               // tile t+1 done; tile t+2 stays in flight
      rawbar();
    } else if (t + 1 < NT) {
      waitvm<0>();                 // last prefetched tile must be complete
      rawbar();
    }
  }
#undef STAGE

  const int rr = (lane >> 4) * 4;
  if (MODE == 0) {
    #pragma unroll
    for (int mi = 0; mi < MI; ++mi) {
      #pragma unroll
      for (int ni = 0; ni < 2; ++ni) {
        const int col = n0 + wc*32 + ni*16 + r0;
        #pragma unroll
        for (int r = 0; r < 4; ++r) {
          const int row = m0 + wr*(TM/2) + mi*16 + rr + r;
          outf[(size_t)row*ldo + col] =
              acc[mi][ni][r] + bf2f(residb[(size_t)row*ldo + col]);
        }
      }
    }
  } else {
    // f32 dtraw side-channel straight from acc (pre-rounding)
    if (n0 == 4352 && wc == 0) {
      #pragma unroll
      for (int ni = 0; ni < 2; ++ni)
        #pragma unroll
        for (int mi = 0; mi < MI; ++mi)
          #pragma unroll
          for (int r = 0; r < 4; ++r) {
            const int row = m0 + wr*(TM/2) + mi*16 + rr + r;
            dtraw[(size_t)row*NH + ni*16 + r0] = acc[mi][ni][r];
          }
    }
    // stage bf16 tile into LDS with granule XOR swizzle, then vector store
    #pragma unroll
    for (int mi = 0; mi < MI; ++mi) {
      #pragma unroll
      for (int ni = 0; ni < 2; ++ni) {
        const int colt = wc*32 + ni*16 + r0;
        #pragma unroll
        for (int r = 0; r < 4; ++r) {
          const int rowt = wr*(TM/2) + mi*16 + rr + r;
          const int g = (colt >> 3) ^ (rowt & 7);
          S[rowt*128 + g*8 + (colt & 7)] = f2bfu(acc[mi][ni][r]);
        }
      }
    }
    __syncthreads();
    const int row = tid >> 2, j4 = tid & 3;
    unsigned short* orow = (unsigned short*)outb + (size_t)(m0 + row)*ldo + n0 + j4*32;
    #pragma unroll
    for (int jj = 0; jj < 4; ++jj) {
      const int g = (j4*4 + jj) ^ (row & 7);
      *(short8*)(orow + jj*8) = *(const short8*)&S[row*128 + g*8];
    }
  }
}

// ---------------- conv1d + silu + dt/ldA prep (bf16 in/out, XCD-contiguous bl) ----------------
__global__ __launch_bounds__(256)
void k_conv(const bf16* __restrict__ zxb, const float* __restrict__ dtraw,
            const float* __restrict__ convw, const float* __restrict__ convb,
            const float* __restrict__ dtb, const float* __restrict__ alog,
            bf16* __restrict__ xs, float* __restrict__ dt,
            float* __restrict__ ldA, bf16* __restrict__ Bc, bf16* __restrict__ Cc)
{
  const int bl = ((blockIdx.x & 7) << 9) | (blockIdx.x >> 3);
  const int l = bl & (LL - 1);
  const int tid = threadIdx.x;
  if (tid < NH) {
    float raw = dtraw[(size_t)bl*NH + tid] + dtb[tid];
    float sp = (raw > 20.f) ? raw : log1pf(__expf(raw));
    float Ah = -__expf(alog[tid]);
    dt[(size_t)bl*NH + tid] = sp;
    ldA[(size_t)bl*NH + tid] = sp * Ah;
  }
  for (int g = tid; g < CONVD/8; g += 256) {     // 288 groups of 8 channels
    const int c0 = g*8;
    float acc[8];
    float4 wv[8];
    #pragma unroll
    for (int e = 0; e < 8; ++e) wv[e] = ((const float4*)convw)[c0 + e];
    {
      const float4 b0 = *(const float4*)(convb + c0);
      const float4 b1 = *(const float4*)(convb + c0 + 4);
      acc[0]=b0.x; acc[1]=b0.y; acc[2]=b0.z; acc[3]=b0.w;
      acc[4]=b1.x; acc[5]=b1.y; acc[6]=b1.z; acc[7]=b1.w;
    }
    #pragma unroll
    for (int k = 0; k < 4; ++k) {
      if (l - 3 + k >= 0) {
        short8 v = *(const short8*)((const unsigned short*)zxb + (size_t)(bl - 3 + k)*DPAD + DI + c0);
        #pragma unroll
        for (int e = 0; e < 8; ++e) {
          const float wk = (k == 0) ? wv[e].x : (k == 1) ? wv[e].y : (k == 2) ? wv[e].z : wv[e].w;
          acc[e] = fmaf(bfu2f((unsigned short)v[e]), wk, acc[e]);
        }
      }
    }
    short8 ov;
    #pragma unroll
    for (int e = 0; e < 8; ++e) {
      const float s = acc[e] / (1.f + __expf(-acc[e]));
      ov[e] = (short)f2bfu(s);
    }
    if (c0 < DI)            *(short8*)((unsigned short*)xs + (size_t)bl*DI + c0) = ov;
    else if (c0 < DI + DS)  *(short8*)((unsigned short*)Bc + (size_t)bl*DS + (c0 - DI)) = ov;
    else                    *(short8*)((unsigned short*)Cc + (size_t)bl*DS + (c0 - DI - DS)) = ov;
  }
}

// ---------------- merged xT-build + scan phase A (MFMA); B transposed in-LDS (no k_bt) ----------------
__global__ __launch_bounds__(512)
void k_xt_state(const bf16* __restrict__ xs, const float* __restrict__ dt,
                const bf16* __restrict__ Bc, const float* __restrict__ ldA,
                unsigned short* __restrict__ Sloc, float* __restrict__ clog)
{
  const int bidx = blockIdx.x;
  const int c = bidx & 15, h = (bidx >> 4) & 31, b = bidx >> 9;
  const int bl0 = b*LL + c*CLEN;
  __shared__ unsigned short LT[128*68];                 // xs*dt, t-major
  __shared__ unsigned short BL[128*132];                // B chunk, t-major
  __shared__ __align__(16) unsigned short XWs[64*136];
  __shared__ float w1[128];
  const int tid = threadIdx.x;
  const int w = tid >> 6, lane = tid & 63;
  const int r0 = lane & 15, kq = (lane >> 4) * 8;
  // stage xs*dt into LT (t-major)
  {
    const int ts = tid >> 3, seg = tid & 7;
    #pragma unroll
    for (int r = 0; r < 2; ++r) {
      const int t = r*64 + ts;
      const float dtv = dt[(size_t)(bl0 + t)*NH + h];
      short8 v = *(const short8*)((const unsigned short*)(xs + (size_t)(bl0 + t)*DI + h*HD) + seg*8);
      unsigned short o[8];
      #pragma unroll
      for (int e = 0; e < 8; ++e)
        o[e] = f2bfu(bfu2f((unsigned short)v[e]) * dtv);
      uint2* d = (uint2*)&LT[t*68 + seg*8];
      d[0] = make_uint2((u32)o[0] | ((u32)o[1] << 16), (u32)o[2] | ((u32)o[3] << 16));
      d[1] = make_uint2((u32)o[4] | ((u32)o[5] << 16), (u32)o[6] | ((u32)o[7] << 16));
    }
  }
  // stage Bc chunk rows into BL (t-major)
  {
    const int t = tid >> 2, q = tid & 3;
    const unsigned short* sb = (const unsigned short*)Bc + (size_t)(bl0 + t)*DS + q*32;
    #pragma unroll
    for (int j = 0; j < 4; ++j)
      *(short8*)&BL[t*132 + q*32 + j*8] = *(const short8*)(sb + j*8);
  }
  // wave 0: shuffle prefix-scan of ldA -> w1 (decay to chunk end)
  if (tid < 64) {
    const int ln = tid;
    const float a0 = ldA[(size_t)(bl0 + 2*ln)*NH + h];
    const float a1 = ldA[(size_t)(bl0 + 2*ln + 1)*NH + h];
    float s = a0 + a1;
    #pragma unroll
    for (int off = 1; off < 64; off <<= 1) {
      const float v = __shfl_up(s, off);
      if (ln >= off) s += v;
    }
    const float Ltot = __shfl(s, 63);
    w1[2*ln + 1] = __expf(Ltot - s);
    w1[2*ln]     = __expf(Ltot - (s - a1));
    if (ln == 63) clog[bidx] = Ltot;
  }
  __syncthreads();
  // gather transposed B fragments from BL (col n = w*16 + r0)
  short8 bfr[4];
  {
    const int n = w*16 + r0;
    #pragma unroll
    for (int kk = 0; kk < 4; ++kk) {
      short8 o;
      #pragma unroll
      for (int e = 0; e < 8; ++e)
        o[e] = (short)BL[(kk*32 + kq + e)*132 + n];
      bfr[kk] = o;
    }
  }
  // transpose LT -> XWs (LDS, scaled by w1)
  {
    const int p = tid >> 3, tg = tid & 7;
    #pragma unroll
    for (int half = 0; half < 2; ++half) {
      short8 oXW;
      #pragma unroll
      for (int e = 0; e < 8; ++e) {
        const int t = tg*16 + half*8 + e;
        oXW[e] = (short)f2bfu(bfu2f(LT[t*68 + p]) * w1[t]);
      }
      *(short8*)&XWs[p*136 + tg*16 + half*8] = oXW;
    }
  }
  __syncthreads();
  f32x4 acc[4] = {};
  #pragma unroll
  for (int kk = 0; kk < 4; ++kk) {
    #pragma unroll
    for (int mi = 0; mi < 4; ++mi) {
      short8 a = *(const short8*)&XWs[(mi*16 + r0)*136 + kk*32 + kq];
      acc[mi] = __builtin_amdgcn_mfma_f32_16x16x32_bf16(a, bfr[kk], acc[mi], 0, 0, 0);
    }
  }
  const int rr = (lane >> 4) * 4;
  unsigned short* So = Sloc + (size_t)bidx*8192;
  #pragma unroll
  for (int mi = 0; mi < 4; ++mi)
    #pragma unroll
    for (int r = 0; r < 4; ++r)
      So[(mi*16 + rr + r)*128 + w*16 + r0] = f2bfu(acc[mi][r]);
}

// ---------------- scan phase B: inter-chunk recurrence (in-place, bf16) ----------------
__global__ __launch_bounds__(256)
void k_chunk_combine(unsigned short* __restrict__ Sloc, const float* __restrict__ clog)
{
  const int bh = blockIdx.x >> 3;
  const int e0 = ((blockIdx.x & 7) * 256 + threadIdx.x) * 4;   // 4 bf16 elems
  float t0 = 0.f, t1 = 0.f, t2 = 0.f, t3 = 0.f;
  for (int c = 0; c < NCHK; ++c) {
    unsigned short* Sp = Sloc + ((size_t)(bh*NCHK + c))*8192 + e0;
    const uint2 raw = *(const uint2*)Sp;
    const float l0 = bfu2f((unsigned short)(raw.x & 0xffff));
    const float l1 = bfu2f((unsigned short)(raw.x >> 16));
    const float l2 = bfu2f((unsigned short)(raw.y & 0xffff));
    const float l3 = bfu2f((unsigned short)(raw.y >> 16));
    uint2 o;
    o.x = (u32)f2bfu(t0) | ((u32)f2bfu(t1) << 16);
    o.y = (u32)f2bfu(t2) | ((u32)f2bfu(t3) << 16);
    *(uint2*)Sp = o;                              // now holds S_init[c]
    const float P = __expf(clog[bh*NCHK + c]);
    t0 = P*t0 + l0; t1 = P*t1 + l1; t2 = P*t2 + l2; t3 = P*t3 + l3;
  }
}

// ---------------- scan phase C (MFMA): Y = M@XD + diag(exp(la))*(C@Sinit^T) + D*x ----------------
// C operand in registers; XD rebuilt in-LDS from xs (no xT global round-trip)
__global__ __launch_bounds__(512)
void k_scan(const bf16* __restrict__ xs, const float* __restrict__ dt,
            const bf16* __restrict__ Bc, const bf16* __restrict__ Cc,
            const unsigned short* __restrict__ Sinit, const float* __restrict__ ldA,
            const float* __restrict__ Dv, unsigned short* __restrict__ y)
{
  const int bidx = blockIdx.x;
  const int c = bidx & 15, h = (bidx >> 4) & 31, b = bidx >> 9;
  const int bl0 = b*LL + c*CLEN;
  __shared__ __align__(16) unsigned short Bs[128*136];   // becomes M after G
  __shared__ __align__(16) unsigned short XDs[64*136];   // first used as X2[128][68]
  __shared__ __align__(16) unsigned short SIs[64*136];
  __shared__ float la[128];
  __shared__ float dts[128];
  const int tid = threadIdx.x;
  const int w = tid >> 6, lane = tid & 63;
  const int r0 = lane & 15, kq = (lane >> 4) * 8;
  // C fragments straight from global (each wave reads only rows w*16+r0)
  short8 cfr[4];
  #pragma unroll
  for (int kk = 0; kk < 4; ++kk)
    cfr[kk] = *(const short8*)((const unsigned short*)Cc
                               + (size_t)(bl0 + w*16 + r0)*DS + kk*32 + kq);
  {
    const int t = tid >> 2, sg = tid & 3;
    const unsigned short* sb = (const unsigned short*)(Bc + (size_t)(bl0 + t)*DS) + sg*32;
    #pragma unroll
    for (int j = 0; j < 4; ++j)
      *(short8*)&Bs[t*136 + sg*32 + j*8] = *(const short8*)(sb + j*8);
  }
  // stage xs rows t-major into XDs-as-X2 [128][68]
  {
    const int t = tid >> 2, q = tid & 3;
    const unsigned short* sx = (const unsigned short*)xs + (size_t)(bl0 + t)*DI + h*HD + q*16;
    *(short8*)&XDs[t*68 + q*16]     = *(const short8*)sx;
    *(short8*)&XDs[t*68 + q*16 + 8] = *(const short8*)(sx + 8);
  }
  if (tid < 128) dts[tid] = dt[(size_t)(bl0 + tid)*NH + h];
  {
    const int p = tid >> 3, seg = tid & 7;
    const unsigned short* sp = Sinit + (size_t)bidx*8192 + p*128 + seg*16;
    *(short8*)&SIs[p*136 + seg*16]     = *(const short8*)sp;
    *(short8*)&SIs[p*136 + seg*16 + 8] = *(const short8*)(sp + 8);
  }
  // wave 0: shuffle prefix-scan of ldA -> inclusive la[]
  if (tid < 64) {
    const int ln = tid;
    const float a0 = ldA[(size_t)(bl0 + 2*ln)*NH + h];
    const float a1 = ldA[(size_t)(bl0 + 2*ln + 1)*NH + h];
    float s = a0 + a1;
    #pragma unroll
    for (int off = 1; off < 64; off <<= 1) {
      const float v = __shfl_up(s, off);
      if (ln >= off) s += v;
    }
    la[2*ln + 1] = s;
    la[2*ln]     = s - a1;
  }
  __syncthreads();
  // transpose X2 -> registers (scaled by dt), then rewrite as XDs [64 p][136]
  float xdv[16];
  {
    const int px = tid >> 3, tg = tid & 7;
    #pragma unroll
    for (int e = 0; e < 16; ++e) {
      const int t = tg*16 + e;
      xdv[e] = bfu2f(XDs[t*68 + px]) * dts[t];
    }
    __syncthreads();
    short8 o0, o1;
    #pragma unroll
    for (int e = 0; e < 8; ++e) { o0[e] = (short)f2bfu(xdv[e]); o1[e] = (short)f2bfu(xdv[8+e]); }
    *(short8*)&XDs[px*136 + tg*16]     = o0;
    *(short8*)&XDs[px*136 + tg*16 + 8] = o1;
  }
  __syncthreads();

  const int trow = w*16 + (lane >> 4) * 4;

  f32x4 aG[8] = {};
  f32x4 aU[4] = {};
  #pragma unroll
  for (int kk = 0; kk < 4; ++kk) {
    #pragma unroll
    for (int sf = 0; sf < 8; ++sf) {
      short8 bb = *(const short8*)&Bs[(sf*16 + r0)*136 + kk*32 + kq];
      aG[sf] = __builtin_amdgcn_mfma_f32_16x16x32_bf16(cfr[kk], bb, aG[sf], 0, 0, 0);
    }
    #pragma unroll
    for (int pf = 0; pf < 4; ++pf) {
      short8 bs = *(const short8*)&SIs[(pf*16 + r0)*136 + kk*32 + kq];
      aU[pf] = __builtin_amdgcn_mfma_f32_16x16x32_bf16(cfr[kk], bs, aU[pf], 0, 0, 0);
    }
  }
  __syncthreads();
  float lat[4];
  #pragma unroll
  for (int r = 0; r < 4; ++r) lat[r] = la[trow + r];
  #pragma unroll
  for (int sf = 0; sf < 8; ++sf) {
    const int s = sf*16 + r0;
    const float las = la[s];
    #pragma unroll
    for (int r = 0; r < 4; ++r) {
      const int t = trow + r;
      const float m = (s <= t) ? aG[sf][r] * __expf(lat[r] - las) : 0.f;
      Bs[t*136 + s] = f2bfu(m);
    }
  }
  __syncthreads();
  f32x4 aY[4] = {};
  #pragma unroll
  for (int kk = 0; kk < 4; ++kk) {
    short8 a = *(const short8*)&Bs[(w*16 + r0)*136 + kk*32 + kq];
    #pragma unroll
    for (int pf = 0; pf < 4; ++pf) {
      short8 bx = *(const short8*)&XDs[(pf*16 + r0)*136 + kk*32 + kq];
      aY[pf] = __builtin_amdgcn_mfma_f32_16x16x32_bf16(a, bx, aY[pf], 0, 0, 0);
    }
  }
  const float Dh = Dv[h];
  float el[4];
  #pragma unroll
  for (int r = 0; r < 4; ++r) el[r] = __expf(lat[r]);
  #pragma unroll
  for (int pf = 0; pf < 4; ++pf) {
    #pragma unroll
    for (int r = 0; r < 4; ++r) {
      const int t = trow + r, p = pf*16 + r0;
      const size_t gi = (size_t)(bl0 + t)*DI + h*HD + p;
      const float yv = aY[pf][r] + el[r]*aU[pf][r] + Dh*bfu2f(((const unsigned short*)xs)[gi]);
      y[gi] = f2bfu(yv);
    }
  }
}

// ---------------- gating + RMSNorm -> bf16 (vectorized, y and z in bf16) ----------------
__global__ __launch_bounds__(256)
void k_gate_norm(const unsigned short* __restrict__ y, const bf16* __restrict__ zxb,
                 const float* __restrict__ nw, bf16* __restrict__ yn)
{
  const size_t bl = blockIdx.x;
  const int tid = threadIdx.x;
  const int c0 = tid * 8;
  short8 yv8 = *(const short8*)(y + bl*DI + c0);
  short8 zv = *(const short8*)((const unsigned short*)zxb + bl*DPAD + c0);
  float v[8];
  float acc = 0.f;
  #pragma unroll
  for (int e = 0; e < 8; ++e) {
    const float zf = bfu2f((unsigned short)zv[e]);
    v[e] = bfu2f((unsigned short)yv8[e]) * (zf / (1.f + __expf(-zf)));
    acc += v[e]*v[e];
  }
  #pragma unroll
  for (int off = 32; off > 0; off >>= 1) acc += __shfl_down(acc, off);
  __shared__ float red[4];
  if ((tid & 63) == 0) red[tid >> 6] = acc;
  __syncthreads();
  const float total = red[0] + red[1] + red[2] + red[3];
  const float r = rsqrtf(total * (1.f/DI) + 1e-5f);
  const float4 w0 = *(const float4*)(nw + c0);
  const float4 w1 = *(const float4*)(nw + c0 + 4);
  const float wv[8] = {w0.x, w0.y, w0.z, w0.w, w1.x, w1.y, w1.z, w1.w};
  short8 ov;
  #pragma unroll
  for (int e = 0; e < 8; ++e) ov[e] = (short)f2bfu(v[e] * r * wv[e]);
  *(short8*)((unsigned short*)yn + bl*DI + c0) = ov;
}

// ---------------- launch ----------------
extern "C" void kernel_launch(void* const* d_in, const int* in_sizes, int n_in,
                              void* d_out, int out_size, void* d_ws, size_t ws_size,
                              hipStream_t stream)
{
  const float* x     = (const float*)d_in[0];
  const float* inw   = (const float*)d_in[1];
  const float* convw = (const float*)d_in[2];
  const float* convb = (const float*)d_in[3];
  const float* dtb   = (const float*)d_in[4];
  const float* alog  = (const float*)d_in[5];
  const float* Dv    = (const float*)d_in[6];
  const float* nw    = (const float*)d_in[7];
  const float* outw  = (const float*)d_in[8];
  float* out = (float*)d_out;
  char* ws = (char*)d_ws;

  constexpr size_t OFF_ZX   = 0;                                       // bf16 [4096][4480]
  constexpr size_t OFF_DTRAW= OFF_ZX   + (size_t)NBL*DPAD*2;           // f32 [4096][32]
  constexpr size_t OFF_XS   = OFF_DTRAW+ (size_t)NBL*NH*4;             // bf16 [4096][2048]
  constexpr size_t OFF_DT   = OFF_XS   + (size_t)NBL*DI*2;             // f32 [4096][32]
  constexpr size_t OFF_LDA  = OFF_DT   + (size_t)NBL*NH*4;             // f32 [4096][32]
  constexpr size_t OFF_B    = OFF_LDA  + (size_t)NBL*NH*4;             // bf16 [4096][128]
  constexpr size_t OFF_C    = OFF_B    + (size_t)NBL*DS*2;             // bf16 [4096][128]
  constexpr size_t OFF_SLOC = OFF_C    + (size_t)NBL*DS*2;             // bf16 [1024][8192]
  constexpr size_t OFF_CLOG = OFF_SLOC + (size_t)1024*8192*2;          // f32 [1024]
  constexpr size_t OFF_Y    = OFF_CLOG + 4096;                         // bf16 [4096][2048]
  constexpr size_t OFF_YN   = OFF_Y    + (size_t)NBL*DI*2;             // bf16 [4096][2048]
  constexpr size_t OFF_XB   = OFF_YN   + (size_t)NBL*DI*2;             // bf16 [4096][1024]
  constexpr size_t OFF_INWB = OFF_XB   + (size_t)NBL*DM*2;             // bf16 [4384][1024]
  constexpr size_t OFF_OUTWB= OFF_INWB + (size_t)DPROJ*DM*2;           // bf16 [1024][2048]

  bf16*  zxb  = (bf16*) (ws + OFF_ZX);
  float* dtraw= (float*)(ws + OFF_DTRAW);
  bf16*  xs   = (bf16*) (ws + OFF_XS);
  float* dt   = (float*)(ws + OFF_DT);
  float* ldA  = (float*)(ws + OFF_LDA);
  bf16*  Bcp  = (bf16*) (ws + OFF_B);
  bf16*  Ccp  = (bf16*) (ws + OFF_C);
  unsigned short* Sloc = (unsigned short*)(ws + OFF_SLOC);
  float* clog = (float*)(ws + OFF_CLOG);
  unsigned short* yb = (unsigned short*)(ws + OFF_Y);
  bf16*  yn   = (bf16*) (ws + OFF_YN);
  bf16*  xb   = (bf16*) (ws + OFF_XB);
  bf16*  inwb = (bf16*) (ws + OFF_INWB);
  bf16*  outwb= (bf16*) (ws + OFF_OUTWB);

  // 0) fused f32 -> bf16 casts
  k_cast3<<<2048, 256, 0, stream>>>(x, xb, NBL*DM/4,
                                    inw, inwb, DPROJ*DM/4,
                                    outw, outwb, DM*DI/4);
  // 1) zxbcdt = x @ in_proj_w^T  (bf16 out + f32 dtraw side-channel)
  k_gemm_nt<128,1><<<dim3(32, 35), 512, 0, stream>>>(xb, inwb, DM, DPROJ, DPAD, nullptr, nullptr, zxb, dtraw);
  // 2) conv + silu + dt/ldA  (bf16 in/out)
  k_conv<<<NBL, 256, 0, stream>>>(zxb, dtraw, convw, convb, dtb, alog, xs, dt, ldA, Bcp, Ccp);
  // 3) chunked scan (MFMA): phase A (B transposed in-LDS), combine, phase C (XD rebuilt in-LDS)
  k_xt_state<<<BB*NH*NCHK, 512, 0, stream>>>(xs, dt, Bcp, ldA, Sloc, clog);
  k_chunk_combine<<<64*8, 256, 0, stream>>>(Sloc, clog);
  k_scan<<<BB*NH*NCHK, 512, 0, stream>>>(xs, dt, Bcp, Ccp, Sloc, ldA, Dv, yb);
  // 4) gating + RMSNorm
  k_gate_norm<<<NBL, 256, 0, stream>>>(yb, zxb, nw, yn);
  // 5) out = x + yn @ out_proj_w^T (bf16 residual)
  k_gemm_nt<64,0><<<dim3(64, 8), 512, 0, stream>>>(yn, outwb, DI, DM, DM, out, xb, nullptr, nullptr);
}

// Round 13
// 194.487 us; speedup vs baseline: 1.0568x; 1.0568x over previous
//
#include <hip/hip_runtime.h>
#include <hip/hip_bf16.h>
#include <cstdint>

typedef __hip_bfloat16 bf16;
typedef __attribute__((ext_vector_type(8))) short short8;
typedef __attribute__((ext_vector_type(4))) float f32x4;
typedef unsigned int u32;

#define BB 2
#define LL 2048
#define DM 1024
#define DI 2048
#define DS 128
#define NH 32
#define HD 64
#define CONVD 2304
#define DPROJ 4384
#define DPAD 4480
#define NBL (BB*LL)
#define NCHK 16
#define CLEN 128

__device__ __forceinline__ float bf2f(bf16 v) { return __bfloat162float(v); }
__device__ __forceinline__ bf16 f2bf(float f) { return __float2bfloat16(f); }
__device__ __forceinline__ unsigned short f2bfu(float f) {
  bf16 t = __float2bfloat16(f); return *(unsigned short*)&t;
}
__device__ __forceinline__ float bfu2f(unsigned short u) {
  u32 b = ((u32)u) << 16; return *(float*)&b;
}

__device__ __forceinline__ void gload16(const void* g, void* l) {
  __builtin_amdgcn_global_load_lds(
      (const __attribute__((address_space(1))) u32*)g,
      (__attribute__((address_space(3))) u32*)l, 16, 0, 0);
}

template<int N> __device__ __forceinline__ void waitvm() {
  __builtin_amdgcn_sched_barrier(0);
  if constexpr (N == 0) asm volatile("s_waitcnt vmcnt(0)" ::: "memory");
  else if constexpr (N == 3) asm volatile("s_waitcnt vmcnt(3)" ::: "memory");
  else if constexpr (N == 4) asm volatile("s_waitcnt vmcnt(4)" ::: "memory");
  __builtin_amdgcn_sched_barrier(0);
}
__device__ __forceinline__ void rawbar() {
  __builtin_amdgcn_sched_barrier(0);
  __builtin_amdgcn_s_barrier();
  __builtin_amdgcn_sched_barrier(0);
}

// ---------------- fused f32 -> bf16 casts (x, in_proj_w, out_proj_w) ----------------
__global__ __launch_bounds__(256)
void k_cast3(const float* __restrict__ s0, bf16* __restrict__ d0, int n0,
             const float* __restrict__ s1, bf16* __restrict__ d1, int n1,
             const float* __restrict__ s2, bf16* __restrict__ d2, int n2)
{
  int i = blockIdx.x * blockDim.x + threadIdx.x;
  const int stride = gridDim.x * blockDim.x;
  const int total = n0 + n1 + n2;
  for (; i < total; i += stride) {
    const float* s; bf16* d; int j = i;
    if (j < n0)            { s = s0; d = d0; }
    else if (j < n0 + n1)  { s = s1; d = d1; j -= n0; }
    else                   { s = s2; d = d2; j -= n0 + n1; }
    const float4 v = ((const float4*)s)[j];
    u32 w0 = (u32)f2bfu(v.x) | ((u32)f2bfu(v.y) << 16);
    u32 w1 = (u32)f2bfu(v.z) | ((u32)f2bfu(v.w) << 16);
    *(uint2*)(d + (size_t)j*4) = make_uint2(w0, w1);
  }
}

// ---------------- GEMM (NT), 8 waves, dbuf + lookahead (counted vmcnt) + LDS swizzle ----------------
// MODE 0: f32 out + bf16 residual. MODE 1: bf16 out (LDS-vectorized) + f32 dtraw side-write.
template<int TM, int MODE>
__global__ __launch_bounds__(512)
void k_gemm_nt(const bf16* __restrict__ A, const bf16* __restrict__ W,
               int K, int Nw, int ldo,
               float* __restrict__ outf, const bf16* __restrict__ residb,
               bf16* __restrict__ outb, float* __restrict__ dtraw)
{
  constexpr int BUFE = (TM + 128) * 64;              // ushorts per buffer
  constexpr int LPT  = TM/64 + 2;                    // gloads per wave per tile
  __shared__ __align__(16) unsigned short S[2*BUFE]; // dbuf; reused as epilogue staging
  const int tid = threadIdx.x;
  const int w = tid >> 6, lane = tid & 63;
  const int m0 = blockIdx.x * TM, n0 = blockIdx.y * 128;
  const int wr = w >> 2, wc = w & 3;                 // 2 (M) x 4 (N) wave grid
  constexpr int MI = TM / 32;
  f32x4 acc[MI][2] = {};
  const int r0 = lane & 15;
  const int kq = (lane >> 4) * 8;
  // swizzle: LDS slot (row, pcol) holds logical col pcol ^ ((row&7)*8); pre-swizzled source.
  const int srow = lane >> 3;
  const int scol = ((lane & 7) ^ (lane >> 3)) << 3;  // pre-swizzled source col (elems)
  const int swz  = (r0 & 7) << 3;                    // read-side XOR (elems)
  const int NT = K >> 6;

#define STAGE(T, BUF) {                                                          \
    const int k0s = (T) << 6;                                                    \
    unsigned short* dst = S + (BUF) * BUFE;                                      \
    _Pragma("unroll")                                                            \
    for (int it = 0; it < TM/64; ++it) {                                         \
      const int seg = it*8 + w;                                                  \
      const int row = seg*8 + srow;                                              \
      gload16(A + (size_t)(m0 + row)*K + (k0s + scol), (char*)dst + seg*1024);   \
    }                                                                            \
    unsigned short* dstW = dst + TM*64;                                          \
    _Pragma("unroll")                                                            \
    for (int it = 0; it < 2; ++it) {                                             \
      const int seg = it*8 + w;                                                  \
      const int row = seg*8 + srow;                                              \
      int rw = n0 + row; rw = (rw < Nw) ? rw : (Nw - 1);                         \
      gload16(W + (size_t)rw*K + (k0s + scol), (char*)dstW + seg*1024);          \
    }                                                                            \
  }

  // prologue: stage tiles 0 and 1
  STAGE(0, 0);
  STAGE(1, 1);
  waitvm<LPT>();          // tile 0 complete, tile 1 still in flight
  rawbar();

  for (int t = 0; t < NT; ++t) {
    const int cur = t & 1;
    const unsigned short* As = S + cur*BUFE;
    const unsigned short* Ws = As + TM*64;
    #pragma unroll
    for (int kk = 0; kk < 64; kk += 32) {
      const int ce = (kk + kq) ^ swz;
      short8 af[MI], bw[2];
      #pragma unroll
      for (int mi = 0; mi < MI; ++mi)
        af[mi] = *(const short8*)(As + (wr*(TM/2) + mi*16 + r0)*64 + ce);
      #pragma unroll
      for (int ni = 0; ni < 2; ++ni)
        bw[ni] = *(const short8*)(Ws + (wc*32 + ni*16 + r0)*64 + ce);
      #pragma unroll
      for (int mi = 0; mi < MI; ++mi)
        #pragma unroll
        for (int ni = 0; ni < 2; ++ni)
          acc[mi][ni] = __builtin_amdgcn_mfma_f32_16x16x32_bf16(af[mi], bw[ni], acc[mi][ni], 0, 0, 0);
    }
    rawbar();                      // all waves done reading buf[cur]
    if (t + 2 < NT) {
      STAGE(t + 2, cur);           // overwrite the buffer just freed
      waitvm<LPT>();               // tile t+1 done; tile t+2 stays in flight
      rawbar();
    } else if (t + 1 < NT) {
      waitvm<0>();                 // last prefetched tile must be complete
      rawbar();
    }
  }
#undef STAGE

  const int rr = (lane >> 4) * 4;
  if (MODE == 0) {
    #pragma unroll
    for (int mi = 0; mi < MI; ++mi) {
      #pragma unroll
      for (int ni = 0; ni < 2; ++ni) {
        const int col = n0 + wc*32 + ni*16 + r0;
        #pragma unroll
        for (int r = 0; r < 4; ++r) {
          const int row = m0 + wr*(TM/2) + mi*16 + rr + r;
          outf[(size_t)row*ldo + col] =
              acc[mi][ni][r] + bf2f(residb[(size_t)row*ldo + col]);
        }
      }
    }
  } else {
    // f32 dtraw side-channel straight from acc (pre-rounding)
    if (n0 == 4352 && wc == 0) {
      #pragma unroll
      for (int ni = 0; ni < 2; ++ni)
        #pragma unroll
        for (int mi = 0; mi < MI; ++mi)
          #pragma unroll
          for (int r = 0; r < 4; ++r) {
            const int row = m0 + wr*(TM/2) + mi*16 + rr + r;
            dtraw[(size_t)row*NH + ni*16 + r0] = acc[mi][ni][r];
          }
    }
    // stage bf16 tile into LDS with granule XOR swizzle, then vector store
    #pragma unroll
    for (int mi = 0; mi < MI; ++mi) {
      #pragma unroll
      for (int ni = 0; ni < 2; ++ni) {
        const int colt = wc*32 + ni*16 + r0;
        #pragma unroll
        for (int r = 0; r < 4; ++r) {
          const int rowt = wr*(TM/2) + mi*16 + rr + r;
          const int g = (colt >> 3) ^ (rowt & 7);
          S[rowt*128 + g*8 + (colt & 7)] = f2bfu(acc[mi][ni][r]);
        }
      }
    }
    __syncthreads();
    const int row = tid >> 2, j4 = tid & 3;
    unsigned short* orow = (unsigned short*)outb + (size_t)(m0 + row)*ldo + n0 + j4*32;
    #pragma unroll
    for (int jj = 0; jj < 4; ++jj) {
      const int g = (j4*4 + jj) ^ (row & 7);
      *(short8*)(orow + jj*8) = *(const short8*)&S[row*128 + g*8];
    }
  }
}

// ---------------- conv1d + silu + dt/ldA prep (bf16 in/out, XCD-contiguous bl) ----------------
__global__ __launch_bounds__(256)
void k_conv(const bf16* __restrict__ zxb, const float* __restrict__ dtraw,
            const float* __restrict__ convw, const float* __restrict__ convb,
            const float* __restrict__ dtb, const float* __restrict__ alog,
            bf16* __restrict__ xs, float* __restrict__ dt,
            float* __restrict__ ldA, bf16* __restrict__ Bc, bf16* __restrict__ Cc)
{
  const int bl = ((blockIdx.x & 7) << 9) | (blockIdx.x >> 3);
  const int l = bl & (LL - 1);
  const int tid = threadIdx.x;
  if (tid < NH) {
    float raw = dtraw[(size_t)bl*NH + tid] + dtb[tid];
    float sp = (raw > 20.f) ? raw : log1pf(__expf(raw));
    float Ah = -__expf(alog[tid]);
    dt[(size_t)bl*NH + tid] = sp;
    ldA[(size_t)bl*NH + tid] = sp * Ah;
  }
  for (int g = tid; g < CONVD/8; g += 256) {     // 288 groups of 8 channels
    const int c0 = g*8;
    float acc[8];
    float4 wv[8];
    #pragma unroll
    for (int e = 0; e < 8; ++e) wv[e] = ((const float4*)convw)[c0 + e];
    {
      const float4 b0 = *(const float4*)(convb + c0);
      const float4 b1 = *(const float4*)(convb + c0 + 4);
      acc[0]=b0.x; acc[1]=b0.y; acc[2]=b0.z; acc[3]=b0.w;
      acc[4]=b1.x; acc[5]=b1.y; acc[6]=b1.z; acc[7]=b1.w;
    }
    #pragma unroll
    for (int k = 0; k < 4; ++k) {
      if (l - 3 + k >= 0) {
        short8 v = *(const short8*)((const unsigned short*)zxb + (size_t)(bl - 3 + k)*DPAD + DI + c0);
        #pragma unroll
        for (int e = 0; e < 8; ++e) {
          const float wk = (k == 0) ? wv[e].x : (k == 1) ? wv[e].y : (k == 2) ? wv[e].z : wv[e].w;
          acc[e] = fmaf(bfu2f((unsigned short)v[e]), wk, acc[e]);
        }
      }
    }
    short8 ov;
    #pragma unroll
    for (int e = 0; e < 8; ++e) {
      const float s = acc[e] / (1.f + __expf(-acc[e]));
      ov[e] = (short)f2bfu(s);
    }
    if (c0 < DI)            *(short8*)((unsigned short*)xs + (size_t)bl*DI + c0) = ov;
    else if (c0 < DI + DS)  *(short8*)((unsigned short*)Bc + (size_t)bl*DS + (c0 - DI)) = ov;
    else                    *(short8*)((unsigned short*)Cc + (size_t)bl*DS + (c0 - DI - DS)) = ov;
  }
}

// ---------------- transpose B per (b,chunk): BT[n][t] = B[t][n] ----------------
__global__ __launch_bounds__(256)
void k_bt(const bf16* __restrict__ Bc, bf16* __restrict__ BT)
{
  const int bidx2 = blockIdx.x;               // b*16 + c
  const int b = bidx2 >> 4, c = bidx2 & 15;
  const int bl0 = b*LL + c*CLEN;
  __shared__ unsigned short LT[128*132];
  const int tid = threadIdx.x;
  {
    const int ts = tid >> 3, seg = tid & 7;
    #pragma unroll
    for (int r = 0; r < 4; ++r) {
      const int t = r*32 + ts;
      const unsigned short* src = (const unsigned short*)(Bc + (size_t)(bl0 + t)*DS);
      short8 v0 = *(const short8*)(src + seg*16);
      short8 v1 = *(const short8*)(src + seg*16 + 8);
      u32 w0 = (u32)(unsigned short)v0[0] | ((u32)(unsigned short)v0[1] << 16);
      u32 w1 = (u32)(unsigned short)v0[2] | ((u32)(unsigned short)v0[3] << 16);
      u32 w2 = (u32)(unsigned short)v0[4] | ((u32)(unsigned short)v0[5] << 16);
      u32 w3 = (u32)(unsigned short)v0[6] | ((u32)(unsigned short)v0[7] << 16);
      u32 w4 = (u32)(unsigned short)v1[0] | ((u32)(unsigned short)v1[1] << 16);
      u32 w5 = (u32)(unsigned short)v1[2] | ((u32)(unsigned short)v1[3] << 16);
      u32 w6 = (u32)(unsigned short)v1[4] | ((u32)(unsigned short)v1[5] << 16);
      u32 w7 = (u32)(unsigned short)v1[6] | ((u32)(unsigned short)v1[7] << 16);
      uint2* d = (uint2*)&LT[t*132 + seg*16];
      d[0] = make_uint2(w0, w1); d[1] = make_uint2(w2, w3);
      d[2] = make_uint2(w4, w5); d[3] = make_uint2(w6, w7);
    }
  }
  __syncthreads();
  {
    const int n = tid >> 1, th = tid & 1;
    unsigned short* dst = (unsigned short*)(BT + (size_t)bidx2*16384 + n*128 + th*64);
    #pragma unroll
    for (int j = 0; j < 8; ++j) {
      short8 o;
      #pragma unroll
      for (int e = 0; e < 8; ++e)
        o[e] = (short)LT[(th*64 + j*8 + e)*132 + n];
      *(short8*)(dst + j*8) = o;
    }
  }
}

// ---------------- merged xT-build + scan phase A (MFMA); BT operand in registers ----------------
__global__ __launch_bounds__(512)
void k_xt_state(const bf16* __restrict__ xs, const float* __restrict__ dt,
                const bf16* __restrict__ BT, const float* __restrict__ ldA,
                bf16* __restrict__ xT, unsigned short* __restrict__ Sloc,
                float* __restrict__ clog)
{
  const int bidx = blockIdx.x;
  const int c = bidx & 15, h = (bidx >> 4) & 31, b = bidx >> 9;
  const int bl0 = b*LL + c*CLEN;
  const int bidx2 = b*NCHK + c;
  __shared__ unsigned short LT[128*68];                 // xs*dt, t-major
  __shared__ __align__(16) unsigned short XWs[64*136];
  __shared__ float w1[128];
  const int tid = threadIdx.x;
  const int w = tid >> 6, lane = tid & 63;
  const int r0 = lane & 15, kq = (lane >> 4) * 8;
  // B-operand fragments straight from global (each wave uses only rows w*16+r0)
  short8 bfr[4];
  #pragma unroll
  for (int kk = 0; kk < 4; ++kk)
    bfr[kk] = *(const short8*)((const unsigned short*)BT + (size_t)bidx2*16384
                               + (size_t)(w*16 + r0)*128 + kk*32 + kq);
  {
    const int ts = tid >> 3, seg = tid & 7;
    #pragma unroll
    for (int r = 0; r < 2; ++r) {
      const int t = r*64 + ts;
      const float dtv = dt[(size_t)(bl0 + t)*NH + h];
      short8 v = *(const short8*)((const unsigned short*)(xs + (size_t)(bl0 + t)*DI + h*HD) + seg*8);
      unsigned short o[8];
      #pragma unroll
      for (int e = 0; e < 8; ++e)
        o[e] = f2bfu(bfu2f((unsigned short)v[e]) * dtv);
      uint2* d = (uint2*)&LT[t*68 + seg*8];
      d[0] = make_uint2((u32)o[0] | ((u32)o[1] << 16), (u32)o[2] | ((u32)o[3] << 16));
      d[1] = make_uint2((u32)o[4] | ((u32)o[5] << 16), (u32)o[6] | ((u32)o[7] << 16));
    }
  }
  if (tid < 64) {
    const int ln = tid;
    const float a0 = ldA[(size_t)(bl0 + 2*ln)*NH + h];
    const float a1 = ldA[(size_t)(bl0 + 2*ln + 1)*NH + h];
    float s = a0 + a1;
    #pragma unroll
    for (int off = 1; off < 64; off <<= 1) {
      const float v = __shfl_up(s, off);
      if (ln >= off) s += v;
    }
    const float Ltot = __shfl(s, 63);
    w1[2*ln + 1] = __expf(Ltot - s);
    w1[2*ln]     = __expf(Ltot - (s - a1));
    if (ln == 63) clog[bidx] = Ltot;
  }
  __syncthreads();
  {
    const int p = tid >> 3, tg = tid & 7;
    unsigned short* xdst = (unsigned short*)xT + (size_t)bidx*8192 + p*128 + tg*16;
    #pragma unroll
    for (int half = 0; half < 2; ++half) {
      short8 oXT, oXW;
      #pragma unroll
      for (int e = 0; e < 8; ++e) {
        const int t = tg*16 + half*8 + e;
        const unsigned short u = LT[t*68 + p];
        oXT[e] = (short)u;
        oXW[e] = (short)f2bfu(bfu2f(u) * w1[t]);
      }
      *(short8*)(xdst + half*8) = oXT;
      *(short8*)&XWs[p*136 + tg*16 + half*8] = oXW;
    }
  }
  __syncthreads();
  f32x4 acc[4] = {};
  #pragma unroll
  for (int kk = 0; kk < 4; ++kk) {
    #pragma unroll
    for (int mi = 0; mi < 4; ++mi) {
      short8 a = *(const short8*)&XWs[(mi*16 + r0)*136 + kk*32 + kq];
      acc[mi] = __builtin_amdgcn_mfma_f32_16x16x32_bf16(a, bfr[kk], acc[mi], 0, 0, 0);
    }
  }
  const int rr = (lane >> 4) * 4;
  unsigned short* So = Sloc + (size_t)bidx*8192;
  #pragma unroll
  for (int mi = 0; mi < 4; ++mi)
    #pragma unroll
    for (int r = 0; r < 4; ++r)
      So[(mi*16 + rr + r)*128 + w*16 + r0] = f2bfu(acc[mi][r]);
}

// ---------------- scan phase B: inter-chunk recurrence (in-place, bf16) ----------------
__global__ __launch_bounds__(256)
void k_chunk_combine(unsigned short* __restrict__ Sloc, const float* __restrict__ clog)
{
  const int bh = blockIdx.x >> 3;
  const int e0 = ((blockIdx.x & 7) * 256 + threadIdx.x) * 4;   // 4 bf16 elems
  float t0 = 0.f, t1 = 0.f, t2 = 0.f, t3 = 0.f;
  for (int c = 0; c < NCHK; ++c) {
    unsigned short* Sp = Sloc + ((size_t)(bh*NCHK + c))*8192 + e0;
    const uint2 raw = *(const uint2*)Sp;
    const float l0 = bfu2f((unsigned short)(raw.x & 0xffff));
    const float l1 = bfu2f((unsigned short)(raw.x >> 16));
    const float l2 = bfu2f((unsigned short)(raw.y & 0xffff));
    const float l3 = bfu2f((unsigned short)(raw.y >> 16));
    uint2 o;
    o.x = (u32)f2bfu(t0) | ((u32)f2bfu(t1) << 16);
    o.y = (u32)f2bfu(t2) | ((u32)f2bfu(t3) << 16);
    *(uint2*)Sp = o;                              // now holds S_init[c]
    const float P = __expf(clog[bh*NCHK + c]);
    t0 = P*t0 + l0; t1 = P*t1 + l1; t2 = P*t2 + l2; t3 = P*t3 + l3;
  }
}

// ---------------- scan phase C (MFMA): Y = M@XD + diag(exp(la))*(C@Sinit^T) + D*x ----------------
// C operand in registers (no Cs LDS buffer -> 2 blocks/CU)
__global__ __launch_bounds__(512)
void k_scan(const bf16* __restrict__ xT, const bf16* __restrict__ Bc,
            const bf16* __restrict__ Cc, const unsigned short* __restrict__ Sinit,
            const float* __restrict__ ldA, const bf16* __restrict__ xs,
            const float* __restrict__ Dv, unsigned short* __restrict__ y)
{
  const int bidx = blockIdx.x;
  const int c = bidx & 15, h = (bidx >> 4) & 31, b = bidx >> 9;
  const int bl0 = b*LL + c*CLEN;
  __shared__ __align__(16) unsigned short Bs[128*136];   // becomes M after G
  __shared__ __align__(16) unsigned short XDs[64*136];
  __shared__ __align__(16) unsigned short SIs[64*136];
  __shared__ float la[128];
  const int tid = threadIdx.x;
  const int w = tid >> 6, lane = tid & 63;
  const int r0 = lane & 15, kq = (lane >> 4) * 8;
  // C fragments straight from global (each wave reads only rows w*16+r0)
  short8 cfr[4];
  #pragma unroll
  for (int kk = 0; kk < 4; ++kk)
    cfr[kk] = *(const short8*)((const unsigned short*)Cc
                               + (size_t)(bl0 + w*16 + r0)*DS + kk*32 + kq);
  {
    const int t = tid >> 2, sg = tid & 3;
    const unsigned short* sb = (const unsigned short*)(Bc + (size_t)(bl0 + t)*DS) + sg*32;
    #pragma unroll
    for (int j = 0; j < 4; ++j)
      *(short8*)&Bs[t*136 + sg*32 + j*8] = *(const short8*)(sb + j*8);
  }
  {
    const int p = tid >> 3, seg = tid & 7;
    const unsigned short* sx = (const unsigned short*)(xT + (size_t)bidx*8192 + p*128) + seg*16;
    *(short8*)&XDs[p*136 + seg*16]     = *(const short8*)sx;
    *(short8*)&XDs[p*136 + seg*16 + 8] = *(const short8*)(sx + 8);
    const unsigned short* sp = Sinit + (size_t)bidx*8192 + p*128 + seg*16;
    *(short8*)&SIs[p*136 + seg*16]     = *(const short8*)sp;
    *(short8*)&SIs[p*136 + seg*16 + 8] = *(const short8*)(sp + 8);
  }
  if (tid < 64) {
    const int ln = tid;
    const float a0 = ldA[(size_t)(bl0 + 2*ln)*NH + h];
    const float a1 = ldA[(size_t)(bl0 + 2*ln + 1)*NH + h];
    float s = a0 + a1;
    #pragma unroll
    for (int off = 1; off < 64; off <<= 1) {
      const float v = __shfl_up(s, off);
      if (ln >= off) s += v;
    }
    la[2*ln + 1] = s;
    la[2*ln]     = s - a1;
  }
  __syncthreads();

  const int trow = w*16 + (lane >> 4) * 4;

  f32x4 aG[8] = {};
  f32x4 aU[4] = {};
  #pragma unroll
  for (int kk = 0; kk < 4; ++kk) {
    #pragma unroll
    for (int sf = 0; sf < 8; ++sf) {
      short8 bb = *(const short8*)&Bs[(sf*16 + r0)*136 + kk*32 + kq];
      aG[sf] = __builtin_amdgcn_mfma_f32_16x16x32_bf16(cfr[kk], bb, aG[sf], 0, 0, 0);
    }
    #pragma unroll
    for (int pf = 0; pf < 4; ++pf) {
      short8 bs = *(const short8*)&SIs[(pf*16 + r0)*136 + kk*32 + kq];
      aU[pf] = __builtin_amdgcn_mfma_f32_16x16x32_bf16(cfr[kk], bs, aU[pf], 0, 0, 0);
    }
  }
  __syncthreads();
  float lat[4];
  #pragma unroll
  for (int r = 0; r < 4; ++r) lat[r] = la[trow + r];
  #pragma unroll
  for (int sf = 0; sf < 8; ++sf) {
    const int s = sf*16 + r0;
    const float las = la[s];
    #pragma unroll
    for (int r = 0; r < 4; ++r) {
      const int t = trow + r;
      const float m = (s <= t) ? aG[sf][r] * __expf(lat[r] - las) : 0.f;
      Bs[t*136 + s] = f2bfu(m);
    }
  }
  __syncthreads();
  f32x4 aY[4] = {};
  #pragma unroll
  for (int kk = 0; kk < 4; ++kk) {
    short8 a = *(const short8*)&Bs[(w*16 + r0)*136 + kk*32 + kq];
    #pragma unroll
    for (int pf = 0; pf < 4; ++pf) {
      short8 bx = *(const short8*)&XDs[(pf*16 + r0)*136 + kk*32 + kq];
      aY[pf] = __builtin_amdgcn_mfma_f32_16x16x32_bf16(a, bx, aY[pf], 0, 0, 0);
    }
  }
  const float Dh = Dv[h];
  float el[4];
  #pragma unroll
  for (int r = 0; r < 4; ++r) el[r] = __expf(lat[r]);
  #pragma unroll
  for (int pf = 0; pf < 4; ++pf) {
    #pragma unroll
    for (int r = 0; r < 4; ++r) {
      const int t = trow + r, p = pf*16 + r0;
      const size_t gi = (size_t)(bl0 + t)*DI + h*HD + p;
      const float yv = aY[pf][r] + el[r]*aU[pf][r] + Dh*bfu2f(((const unsigned short*)xs)[gi]);
      y[gi] = f2bfu(yv);
    }
  }
}

// ---------------- gating + RMSNorm -> bf16 (vectorized, y and z in bf16) ----------------
__global__ __launch_bounds__(256)
void k_gate_norm(const unsigned short* __restrict__ y, const bf16* __restrict__ zxb,
                 const float* __restrict__ nw, bf16* __restrict__ yn)
{
  const size_t bl = blockIdx.x;
  const int tid = threadIdx.x;
  const int c0 = tid * 8;
  short8 yv8 = *(const short8*)(y + bl*DI + c0);
  short8 zv = *(const short8*)((const unsigned short*)zxb + bl*DPAD + c0);
  float v[8];
  float acc = 0.f;
  #pragma unroll
  for (int e = 0; e < 8; ++e) {
    const float zf = bfu2f((unsigned short)zv[e]);
    v[e] = bfu2f((unsigned short)yv8[e]) * (zf / (1.f + __expf(-zf)));
    acc += v[e]*v[e];
  }
  #pragma unroll
  for (int off = 32; off > 0; off >>= 1) acc += __shfl_down(acc, off);
  __shared__ float red[4];
  if ((tid & 63) == 0) red[tid >> 6] = acc;
  __syncthreads();
  const float total = red[0] + red[1] + red[2] + red[3];
  const float r = rsqrtf(total * (1.f/DI) + 1e-5f);
  const float4 w0 = *(const float4*)(nw + c0);
  const float4 w1 = *(const float4*)(nw + c0 + 4);
  const float wv[8] = {w0.x, w0.y, w0.z, w0.w, w1.x, w1.y, w1.z, w1.w};
  short8 ov;
  #pragma unroll
  for (int e = 0; e < 8; ++e) ov[e] = (short)f2bfu(v[e] * r * wv[e]);
  *(short8*)((unsigned short*)yn + bl*DI + c0) = ov;
}

// ---------------- launch ----------------
extern "C" void kernel_launch(void* const* d_in, const int* in_sizes, int n_in,
                              void* d_out, int out_size, void* d_ws, size_t ws_size,
                              hipStream_t stream)
{
  const float* x     = (const float*)d_in[0];
  const float* inw   = (const float*)d_in[1];
  const float* convw = (const float*)d_in[2];
  const float* convb = (const float*)d_in[3];
  const float* dtb   = (const float*)d_in[4];
  const float* alog  = (const float*)d_in[5];
  const float* Dv    = (const float*)d_in[6];
  const float* nw    = (const float*)d_in[7];
  const float* outw  = (const float*)d_in[8];
  float* out = (float*)d_out;
  char* ws = (char*)d_ws;

  constexpr size_t OFF_ZX   = 0;                                       // bf16 [4096][4480]
  constexpr size_t OFF_DTRAW= OFF_ZX   + (size_t)NBL*DPAD*2;           // f32 [4096][32]
  constexpr size_t OFF_XS   = OFF_DTRAW+ (size_t)NBL*NH*4;             // bf16 [4096][2048]
  constexpr size_t OFF_DT   = OFF_XS   + (size_t)NBL*DI*2;             // f32 [4096][32]
  constexpr size_t OFF_LDA  = OFF_DT   + (size_t)NBL*NH*4;             // f32 [4096][32]
  constexpr size_t OFF_B    = OFF_LDA  + (size_t)NBL*NH*4;             // bf16 [4096][128]
  constexpr size_t OFF_C    = OFF_B    + (size_t)NBL*DS*2;             // bf16 [4096][128]
  constexpr size_t OFF_XT   = OFF_C    + (size_t)NBL*DS*2;             // bf16 [1024][64][128]
  constexpr size_t OFF_BT   = OFF_XT   + (size_t)1024*8192*2;          // bf16 [32][128][128]
  constexpr size_t OFF_SLOC = OFF_BT   + (size_t)32*16384*2;           // bf16 [1024][8192]
  constexpr size_t OFF_CLOG = OFF_SLOC + (size_t)1024*8192*2;          // f32 [1024]
  constexpr size_t OFF_Y    = OFF_CLOG + 4096;                         // bf16 [4096][2048]
  constexpr size_t OFF_YN   = OFF_Y    + (size_t)NBL*DI*2;             // bf16 [4096][2048]
  constexpr size_t OFF_XB   = OFF_YN   + (size_t)NBL*DI*2;             // bf16 [4096][1024]
  constexpr size_t OFF_INWB = OFF_XB   + (size_t)NBL*DM*2;             // bf16 [4384][1024]
  constexpr size_t OFF_OUTWB= OFF_INWB + (size_t)DPROJ*DM*2;           // bf16 [1024][2048]

  bf16*  zxb  = (bf16*) (ws + OFF_ZX);
  float* dtraw= (float*)(ws + OFF_DTRAW);
  bf16*  xs   = (bf16*) (ws + OFF_XS);
  float* dt   = (float*)(ws + OFF_DT);
  float* ldA  = (float*)(ws + OFF_LDA);
  bf16*  Bcp  = (bf16*) (ws + OFF_B);
  bf16*  Ccp  = (bf16*) (ws + OFF_C);
  bf16*  xT   = (bf16*) (ws + OFF_XT);
  bf16*  BT   = (bf16*) (ws + OFF_BT);
  unsigned short* Sloc = (unsigned short*)(ws + OFF_SLOC);
  float* clog = (float*)(ws + OFF_CLOG);
  unsigned short* yb = (unsigned short*)(ws + OFF_Y);
  bf16*  yn   = (bf16*) (ws + OFF_YN);
  bf16*  xb   = (bf16*) (ws + OFF_XB);
  bf16*  inwb = (bf16*) (ws + OFF_INWB);
  bf16*  outwb= (bf16*) (ws + OFF_OUTWB);

  // 0) fused f32 -> bf16 casts
  k_cast3<<<2048, 256, 0, stream>>>(x, xb, NBL*DM/4,
                                    inw, inwb, DPROJ*DM/4,
                                    outw, outwb, DM*DI/4);
  // 1) zxbcdt = x @ in_proj_w^T  (bf16 out + f32 dtraw side-channel)
  k_gemm_nt<128,1><<<dim3(32, 35), 512, 0, stream>>>(xb, inwb, DM, DPROJ, DPAD, nullptr, nullptr, zxb, dtraw);
  // 2) conv + silu + dt/ldA  (bf16 in/out)
  k_conv<<<NBL, 256, 0, stream>>>(zxb, dtraw, convw, convb, dtb, alog, xs, dt, ldA, Bcp, Ccp);
  // 3) B transpose for phase A
  k_bt<<<BB*NCHK, 256, 0, stream>>>(Bcp, BT);
  // 4) chunked scan (MFMA): merged xT-build + phase A, combine, phase C
  k_xt_state<<<BB*NH*NCHK, 512, 0, stream>>>(xs, dt, BT, ldA, xT, Sloc, clog);
  k_chunk_combine<<<64*8, 256, 0, stream>>>(Sloc, clog);
  k_scan<<<BB*NH*NCHK, 512, 0, stream>>>(xT, Bcp, Ccp, Sloc, ldA, xs, Dv, yb);
  // 5) gating + RMSNorm
  k_gate_norm<<<NBL, 256, 0, stream>>>(yb, zxb, nw, yn);
  // 6) out = x + yn @ out_proj_w^T (bf16 residual)
  k_gemm_nt<64,0><<<dim3(64, 8), 512, 0, stream>>>(yn, outwb, DI, DM, DM, out, xb, nullptr, nullptr);
}